// Round 1
// baseline (1688.933 us; speedup 1.0000x reference)
//
#include <hip/hip_runtime.h>

#define BATCH 8

__global__ void fx_kernel(const float* __restrict__ values,
                          float* __restrict__ fx, int bn) {
    int i = blockIdx.x * blockDim.x + threadIdx.x;
    if (i < bn) fx[i] = tanhf(values[i]);
}

// pred[b*N + tgt] += w[e] * fx[b*N + src]
__global__ void scatter_pred_kernel(const float* __restrict__ fx,
                                    const float* __restrict__ w,
                                    const int* __restrict__ idx,
                                    float* __restrict__ pred,
                                    int E, int N) {
    int e = blockIdx.x * blockDim.x + threadIdx.x;
    if (e >= E) return;
    int s = idx[e];       // src = edge_index[0, e]
    int t = idx[E + e];   // tgt = edge_index[1, e]
    float we = w[e];
#pragma unroll
    for (int b = 0; b < BATCH; ++b) {
        atomicAdd(&pred[b * N + t], we * fx[b * N + s]);
    }
}

__global__ void err_kernel(const float* __restrict__ values,
                           const float* __restrict__ pred,
                           float* __restrict__ err, int bn) {
    int i = blockIdx.x * blockDim.x + threadIdx.x;
    if (i < bn) err[i] = values[i] - pred[i];
}

// aggr[b*N + src] += w[e] * err[b*N + tgt]
__global__ void scatter_aggr_kernel(const float* __restrict__ err,
                                    const float* __restrict__ w,
                                    const int* __restrict__ idx,
                                    float* __restrict__ aggr,
                                    int E, int N) {
    int e = blockIdx.x * blockDim.x + threadIdx.x;
    if (e >= E) return;
    int s = idx[e];
    int t = idx[E + e];
    float we = w[e];
#pragma unroll
    for (int b = 0; b < BATCH; ++b) {
        atomicAdd(&aggr[b * N + s], we * err[b * N + t]);
    }
}

__global__ void dx_kernel(const float* __restrict__ fx,
                          const float* __restrict__ err,
                          const float* __restrict__ aggr,
                          float* __restrict__ dx, int bn) {
    int i = blockIdx.x * blockDim.x + threadIdx.x;
    if (i < bn) {
        float f = fx[i];
        float fprime = 1.0f - f * f;
        dx[i] = err[i] - fprime * aggr[i];
    }
}

extern "C" void kernel_launch(void* const* d_in, const int* in_sizes, int n_in,
                              void* d_out, int out_size, void* d_ws, size_t ws_size,
                              hipStream_t stream) {
    const float* values  = (const float*)d_in[0];   // [B*N]
    const float* weights = (const float*)d_in[1];   // [E]
    const int*   edge_ix = (const int*)d_in[2];     // [2, E]

    const int BN = in_sizes[0];        // B*N = 80000
    const int E  = in_sizes[1];        // 2,000,000
    const int N  = BN / BATCH;         // 10000

    float* out  = (float*)d_out;       // [3, B*N]
    float* pred = out;                 // slice 0
    float* err  = out + BN;            // slice 1
    float* dx   = out + 2 * BN;        // slice 2

    float* fx   = (float*)d_ws;        // B*N floats
    float* aggr = fx + BN;             // B*N floats

    // zero the accumulation targets (ws/out are poisoned to 0xAA each call)
    hipMemsetAsync(pred, 0, (size_t)BN * sizeof(float), stream);
    hipMemsetAsync(aggr, 0, (size_t)BN * sizeof(float), stream);

    const int TB = 256;
    fx_kernel<<<(BN + TB - 1) / TB, TB, 0, stream>>>(values, fx, BN);
    scatter_pred_kernel<<<(E + TB - 1) / TB, TB, 0, stream>>>(fx, weights, edge_ix, pred, E, N);
    err_kernel<<<(BN + TB - 1) / TB, TB, 0, stream>>>(values, pred, err, BN);
    scatter_aggr_kernel<<<(E + TB - 1) / TB, TB, 0, stream>>>(err, weights, edge_ix, aggr, E, N);
    dx_kernel<<<(BN + TB - 1) / TB, TB, 0, stream>>>(fx, err, aggr, dx, BN);
}

// Round 2
// 307.426 us; speedup vs baseline: 5.4938x; 5.4938x over previous
//
#include <hip/hip_runtime.h>

#define BATCH 8
#define NN 10000      // nodes per graph (asserted against in_sizes at launch)
#define TB 256

__global__ void fx_kernel(const float* __restrict__ values,
                          float* __restrict__ fx, int bn) {
    int i = blockIdx.x * blockDim.x + threadIdx.x;
    if (i < bn) fx[i] = tanhf(values[i]);
}

// One block = (edge-chunk k, batch b). Accumulate w[e]*g[gather_idx] into an
// LDS array covering ALL N nodes, then flush partial sums (no global atomics).
// partial layout: partial[k*BN + b*N + i]
__global__ __launch_bounds__(TB) void scatter_lds_kernel(
        const float* __restrict__ gsrc,   // gather base [B*N] (fx or err)
        const float* __restrict__ w,      // [E]
        const int* __restrict__ idx,      // [2,E]
        float* __restrict__ partial,
        int E, int N, int chunk,
        long gather_off, long scatter_off)
{
    __shared__ float acc[NN];
    for (int i = threadIdx.x; i < N; i += TB) acc[i] = 0.0f;
    __syncthreads();

    const int k = blockIdx.x, b = blockIdx.y;
    const float* __restrict__ g = gsrc + (long)b * N;
    long e0 = (long)k * chunk;
    long e1 = e0 + chunk;
    if (e1 > E) e1 = E;

    for (long e = e0 + threadIdx.x; e < e1; e += TB) {
        int gi = idx[e + gather_off];    // coalesced index load
        int si = idx[e + scatter_off];   // coalesced index load
        atomicAdd(&acc[si], w[e] * g[gi]);  // LDS atomic (ds_add_f32)
    }
    __syncthreads();

    float* __restrict__ p = partial + ((long)k * BATCH + b) * N;
    for (int i = threadIdx.x; i < N; i += TB) p[i] = acc[i];  // coalesced
}

// pred[j] = sum_k partial[k*BN+j];  err[j] = values[j] - pred[j]
__global__ void reduce_pred_err_kernel(const float* __restrict__ partial,
                                       const float* __restrict__ values,
                                       float* __restrict__ pred,
                                       float* __restrict__ err,
                                       int BN, int K) {
    int j = blockIdx.x * blockDim.x + threadIdx.x;
    if (j >= BN) return;
    float s = 0.0f;
    for (int k = 0; k < K; ++k) s += partial[(long)k * BN + j];
    pred[j] = s;
    err[j] = values[j] - s;
}

// aggr[j] = sum_k partial[k*BN+j];  dx[j] = err[j] - (1-fx^2)*aggr
__global__ void reduce_dx_kernel(const float* __restrict__ partial,
                                 const float* __restrict__ fx,
                                 const float* __restrict__ err,
                                 float* __restrict__ dx,
                                 int BN, int K) {
    int j = blockIdx.x * blockDim.x + threadIdx.x;
    if (j >= BN) return;
    float s = 0.0f;
    for (int k = 0; k < K; ++k) s += partial[(long)k * BN + j];
    float f = fx[j];
    dx[j] = err[j] - (1.0f - f * f) * s;
}

extern "C" void kernel_launch(void* const* d_in, const int* in_sizes, int n_in,
                              void* d_out, int out_size, void* d_ws, size_t ws_size,
                              hipStream_t stream) {
    const float* values  = (const float*)d_in[0];   // [B*N]
    const float* weights = (const float*)d_in[1];   // [E]
    const int*   edge_ix = (const int*)d_in[2];     // [2, E]

    const int BN = in_sizes[0];        // 80000
    const int E  = in_sizes[1];        // 2,000,000
    const int N  = BN / BATCH;         // 10000

    float* out  = (float*)d_out;       // [3, B*N]
    float* pred = out;
    float* err  = out + BN;
    float* dx   = out + 2 * BN;

    float* fx      = (float*)d_ws;               // BN floats
    float* partial = fx + BN;                    // K*BN floats

    // Pick K (edge chunks) to fit workspace; deterministic across calls.
    size_t fx_bytes = (size_t)BN * sizeof(float);
    int K = 128;
    while (K > 8 && fx_bytes + (size_t)K * BN * sizeof(float) > ws_size) K >>= 1;
    const int chunk = (E + K - 1) / K;

    fx_kernel<<<(BN + TB - 1) / TB, TB, 0, stream>>>(values, fx, BN);

    dim3 sgrid(K, BATCH);
    // Phase 1: gather fx at src (row 0), scatter to tgt (row 1)
    scatter_lds_kernel<<<sgrid, TB, 0, stream>>>(fx, weights, edge_ix, partial,
                                                 E, N, chunk, 0L, (long)E);
    reduce_pred_err_kernel<<<(BN + TB - 1) / TB, TB, 0, stream>>>(
        partial, values, pred, err, BN, K);

    // Phase 2: gather err at tgt (row 1), scatter to src (row 0)
    scatter_lds_kernel<<<sgrid, TB, 0, stream>>>(err, weights, edge_ix, partial,
                                                 E, N, chunk, (long)E, 0L);
    reduce_dx_kernel<<<(BN + TB - 1) / TB, TB, 0, stream>>>(
        partial, fx, err, dx, BN, K);
}